// Round 5
// baseline (885.300 us; speedup 1.0000x reference)
//
#include <hip/hip_runtime.h>

// Problem constants: B=32, S=512, L=20, T=16, E=300, H=128, D=128, V=50000

// Raw workgroup barrier: orders LDS ops (lgkmcnt drain) but does NOT drain
// vmcnt — keeps prefetch global-loads and fire-and-forget stores in flight.
#define LDS_BARRIER() do {                                   \
    asm volatile("s_waitcnt lgkmcnt(0)" ::: "memory");       \
    __builtin_amdgcn_s_barrier();                            \
    asm volatile("" ::: "memory");                           \
  } while (0)

// ---------------------------------------------------------------------------
// K1: sentence embedding mean.  grid = B*S blocks, 128 threads.
// ---------------------------------------------------------------------------
__global__ __launch_bounds__(128) void k_sent_mean(
    const int* __restrict__ wid, const float* __restrict__ emb,
    float* __restrict__ sent)
{
  const int bs = blockIdx.x;
  const int tid = threadIdx.x;
  const int* w = wid + (size_t)bs * 20;
  float a0 = 0.f, a1 = 0.f, a2 = 0.f;
  for (int l = 0; l < 20; ++l) {
    const float* row = emb + (size_t)w[l] * 300;
    a0 += row[tid];
    a1 += row[tid + 128];
    if (tid < 44) a2 += row[tid + 256];
  }
  const float inv = 1.0f / 20.0f;
  float* o = sent + (size_t)bs * 300;
  o[tid] = a0 * inv;
  o[tid + 128] = a1 * inv;
  if (tid < 44) o[tid + 256] = a2 * inv;
}

// ---------------------------------------------------------------------------
// K2: generic fp32 tiled GEMM.  C[M,N] = A[M,K] @ B + bias, optional relu.
// BT=true : B is (N,K) row-major -> C=A@B^T ;  BT=false: B is (K,N) -> C=A@B
// 64x64 tile, 256 threads, 4x4 micro-tile, K chunked by 64.  N % 64 == 0.
// ---------------------------------------------------------------------------
template<bool BT, int ACT>
__global__ __launch_bounds__(256) void k_gemm(
    const int M, const int N, const int K,
    const float* __restrict__ A, const int lda,
    const float* __restrict__ Bm, const int ldb,
    float* __restrict__ C, const int ldc,
    const float* __restrict__ bias)
{
  (void)N;
  __shared__ float As[64][68];
  __shared__ float Bs[64][68];
  const int tid = threadIdx.x;
  const int m0 = blockIdx.x * 64;
  const int n0 = blockIdx.y * 64;
  const int tx = tid & 15;
  const int ty = tid >> 4;
  float acc[4][4] = {};

  for (int kc = 0; kc < K; kc += 64) {
    const int kb = (K - kc < 64) ? (K - kc) : 64;
    #pragma unroll
    for (int r = 0; r < 4; ++r) {
      const int m = r * 16 + ty;
      const int k4 = tx * 4;
      float4 v = make_float4(0.f, 0.f, 0.f, 0.f);
      if (m0 + m < M) {
        const float* ap = A + (size_t)(m0 + m) * lda + kc;
        if (k4 + 4 <= kb) {
          v = *(const float4*)(ap + k4);
        } else {
          float t0 = (k4 + 0 < kb) ? ap[k4 + 0] : 0.f;
          float t1 = (k4 + 1 < kb) ? ap[k4 + 1] : 0.f;
          float t2 = (k4 + 2 < kb) ? ap[k4 + 2] : 0.f;
          float t3 = (k4 + 3 < kb) ? ap[k4 + 3] : 0.f;
          v = make_float4(t0, t1, t2, t3);
        }
      }
      *(float4*)&As[m][k4] = v;
    }
    if (BT) {
      #pragma unroll
      for (int r = 0; r < 4; ++r) {
        const int n = r * 16 + ty;
        const int k4 = tx * 4;
        float4 v = make_float4(0.f, 0.f, 0.f, 0.f);
        const float* bp = Bm + (size_t)(n0 + n) * ldb + kc;
        if (k4 + 4 <= kb) {
          v = *(const float4*)(bp + k4);
        } else {
          float t0 = (k4 + 0 < kb) ? bp[k4 + 0] : 0.f;
          float t1 = (k4 + 1 < kb) ? bp[k4 + 1] : 0.f;
          float t2 = (k4 + 2 < kb) ? bp[k4 + 2] : 0.f;
          float t3 = (k4 + 3 < kb) ? bp[k4 + 3] : 0.f;
          v = make_float4(t0, t1, t2, t3);
        }
        Bs[k4 + 0][n] = v.x;
        Bs[k4 + 1][n] = v.y;
        Bs[k4 + 2][n] = v.z;
        Bs[k4 + 3][n] = v.w;
      }
    } else {
      #pragma unroll
      for (int r = 0; r < 4; ++r) {
        const int kk = r * 16 + ty;
        const int n4 = tx * 4;
        float4 v = make_float4(0.f, 0.f, 0.f, 0.f);
        if (kk < kb) v = *(const float4*)(Bm + (size_t)(kc + kk) * ldb + n0 + n4);
        *(float4*)&Bs[kk][n4] = v;
      }
    }
    __syncthreads();
    #pragma unroll 4
    for (int kk = 0; kk < kb; ++kk) {
      const float4 bv = *(const float4*)&Bs[kk][tx * 4];
      #pragma unroll
      for (int i = 0; i < 4; ++i) {
        const float a = As[ty * 4 + i][kk];
        acc[i][0] = fmaf(a, bv.x, acc[i][0]);
        acc[i][1] = fmaf(a, bv.y, acc[i][1]);
        acc[i][2] = fmaf(a, bv.z, acc[i][2]);
        acc[i][3] = fmaf(a, bv.w, acc[i][3]);
      }
    }
    __syncthreads();
  }

  float bv4[4] = {0.f, 0.f, 0.f, 0.f};
  if (bias != nullptr) {
    #pragma unroll
    for (int j = 0; j < 4; ++j) bv4[j] = bias[n0 + tx * 4 + j];
  }
  #pragma unroll
  for (int i = 0; i < 4; ++i) {
    const int m = m0 + ty * 4 + i;
    if (m < M) {
      float4 o;
      o.x = acc[i][0] + bv4[0];
      o.y = acc[i][1] + bv4[1];
      o.z = acc[i][2] + bv4[2];
      o.w = acc[i][3] + bv4[3];
      if (ACT == 1) {
        o.x = fmaxf(o.x, 0.f); o.y = fmaxf(o.y, 0.f);
        o.z = fmaxf(o.z, 0.f); o.w = fmaxf(o.w, 0.f);
      }
      *(float4*)&C[(size_t)m * ldc + n0 + tx * 4] = o;
    }
  }
}

// ---------------------------------------------------------------------------
// K3: GRU recurrence, one block per (batch, direction).  grid = 64, 256 thr.
//
// LDS-instruction-minimized layout (round-4 postmortem: the LDS pipe was the
// bottleneck at ~220 instr/step; each lane owning 1 row forces 1 b128
// broadcast per 4 FMA-instr).  Here each lane owns THREE rows x 64-K-slice:
//   wave w: kh = w&1 (K-half), rg = w>>1 (rows rg*192..rg*192+191)
//   lane ln: rows r0=rg*192+ln, r0+64, r0+128 -> 192 register-resident weights
// Per step: 16 b128 h-broadcasts per wave (64 total, each feeding 12 FMAs),
// partials in interleaved part2[row][kh] (b64 gate reads, conflict-free),
// h held in gate-thread registers.  ~92 LDS instr/step vs ~220 before.
// gi double-buffered in 32-step chunks via register staging; raw lgkmcnt
// barriers only (no vmcnt drain on the critical path).
// ---------------------------------------------------------------------------
__global__ __launch_bounds__(256, 1) void k_gru(
    const float* __restrict__ gi_f, const float* __restrict__ gi_b,
    const float* __restrict__ Wh_f, const float* __restrict__ Wh_b,
    const float* __restrict__ bh_f, const float* __restrict__ bh_b,
    float* __restrict__ srep, float* __restrict__ hfin)
{
  const int dir = blockIdx.x & 1;
  const int b = blockIdx.x >> 1;
  const float* gi = (dir ? gi_b : gi_f) + (size_t)b * 512 * 384;
  const float* Wh = dir ? Wh_b : Wh_f;
  const float* bh = dir ? bh_b : bh_f;

  const int tid = threadIdx.x;
  const int wv = tid >> 6;
  const int ln = tid & 63;
  const int kh = wv & 1;        // K-half: floats kh*64 .. kh*64+63
  const int rg = wv >> 1;       // row-group: rows rg*192 .. rg*192+191
  const int r0 = rg * 192 + ln; // this lane's rows: r0, r0+64, r0+128

  __shared__ __align__(16) float hlds[128];
  __shared__ __align__(8)  float part2[384 * 2];     // [row][kh] interleaved
  __shared__ __align__(16) float gis[2][32 * 384];   // 2 x 48 KB

  // register-resident weights: 3 rows x 64-K-slice = 48 float4
  float4 w0[16], w1[16], w2[16];
  {
    const float* p = Wh + (size_t)r0 * 128 + kh * 64;
    #pragma unroll
    for (int kk = 0; kk < 16; ++kk) w0[kk] = *(const float4*)(p + kk * 4);
    p += 64 * 128;
    #pragma unroll
    for (int kk = 0; kk < 16; ++kk) w1[kk] = *(const float4*)(p + kk * 4);
    p += 64 * 128;
    #pragma unroll
    for (int kk = 0; kk < 16; ++kk) w2[kk] = *(const float4*)(p + kk * 4);
  }
  const float bh0 = kh ? 0.f : bh[r0];
  const float bh1 = kh ? 0.f : bh[r0 + 64];
  const float bh2 = kh ? 0.f : bh[r0 + 128];

  // prologue: stage chunk 0 synchronously
  {
    const int lo0 = dir ? 480 : 0;
    const float4* g4 = (const float4*)(gi + (size_t)lo0 * 384);
    float4* l4 = (float4*)gis[0];
    #pragma unroll
    for (int j = 0; j < 12; ++j) l4[j * 256 + tid] = g4[j * 256 + tid];
  }
  float hreg = 0.f;
  if (tid < 128) hlds[tid] = 0.f;
  LDS_BARRIER();

  const float4* h4 = (const float4*)hlds + kh * 16;
  float4 stg[12];

  for (int c = 0; c < 16; ++c) {
    const int buf = c & 1;
    const int lo = dir ? (480 - 32 * c) : (32 * c);
    // issue next chunk's global loads (held in regs; consumed at chunk end)
    if (c < 15) {
      const int lon = dir ? (480 - 32 * (c + 1)) : (32 * (c + 1));
      const float4* g4 = (const float4*)(gi + (size_t)lon * 384);
      #pragma unroll
      for (int j = 0; j < 12; ++j) stg[j] = g4[j * 256 + tid];
    }

    for (int i = 0; i < 32; ++i) {
      const int sloc = dir ? (31 - i) : i;    // row within chunk
      const int seq = lo + sloc;              // absolute sequence index

      float4 A0 = {0.f, 0.f, 0.f, 0.f};
      float4 A1 = {0.f, 0.f, 0.f, 0.f};
      float4 A2 = {0.f, 0.f, 0.f, 0.f};
      #pragma unroll
      for (int kk = 0; kk < 16; ++kk) {
        const float4 hv = h4[kk];               // 1 b128 broadcast -> 12 FMA
        A0.x = fmaf(w0[kk].x, hv.x, A0.x);
        A0.y = fmaf(w0[kk].y, hv.y, A0.y);
        A0.z = fmaf(w0[kk].z, hv.z, A0.z);
        A0.w = fmaf(w0[kk].w, hv.w, A0.w);
        A1.x = fmaf(w1[kk].x, hv.x, A1.x);
        A1.y = fmaf(w1[kk].y, hv.y, A1.y);
        A1.z = fmaf(w1[kk].z, hv.z, A1.z);
        A1.w = fmaf(w1[kk].w, hv.w, A1.w);
        A2.x = fmaf(w2[kk].x, hv.x, A2.x);
        A2.y = fmaf(w2[kk].y, hv.y, A2.y);
        A2.z = fmaf(w2[kk].z, hv.z, A2.z);
        A2.w = fmaf(w2[kk].w, hv.w, A2.w);
      }
      part2[r0 * 2 + kh]         = (A0.x + A0.y) + (A0.z + A0.w) + bh0;
      part2[(r0 + 64) * 2 + kh]  = (A1.x + A1.y) + (A1.z + A1.w) + bh1;
      part2[(r0 + 128) * 2 + kh] = (A2.x + A2.y) + (A2.z + A2.w) + bh2;
      LDS_BARRIER();

      if (tid < 128) {
        const float* grow = &gis[buf][sloc * 384];
        const float2 pr = *(const float2*)&part2[tid * 2];
        const float2 pz = *(const float2*)&part2[(tid + 128) * 2];
        const float2 pn = *(const float2*)&part2[(tid + 256) * 2];
        const float gir = grow[tid];
        const float giz = grow[tid + 128];
        const float gin = grow[tid + 256];
        const float r = 1.f / (1.f + expf(-(gir + (pr.x + pr.y))));
        const float z = 1.f / (1.f + expf(-(giz + (pz.x + pz.y))));
        const float n = tanhf(gin + r * (pn.x + pn.y));
        hreg = (1.f - z) * n + z * hreg;
        hlds[tid] = hreg;
        srep[((size_t)(b * 512 + seq)) * 256 + dir * 128 + tid] = hreg;
      }
      LDS_BARRIER();
    }

    // write staged next chunk into the buffer we just finished reading
    if (c < 15) {
      float4* l4 = (float4*)gis[buf ^ 1];
      #pragma unroll
      for (int j = 0; j < 12; ++j) l4[j * 256 + tid] = stg[j];
      LDS_BARRIER();
    }
  }
  if (tid < 128) hfin[(size_t)dir * 4096 + (size_t)b * 128 + tid] = hreg;
}

// ---------------------------------------------------------------------------
// K4: topic boundary diffs.  grid = B*T = 512, 256 threads.
// ---------------------------------------------------------------------------
__global__ __launch_bounds__(256) void k_topic(
    const int* __restrict__ starts, const int* __restrict__ ends,
    const float* __restrict__ srep, float* __restrict__ tmat)
{
  const int bt = blockIdx.x;
  const int b = bt >> 4;
  const int st = starts[bt], en = ends[bt];
  const int j = threadIdx.x;
  float v;
  if (j < 128) {
    const float a = (en >= 1 && en <= 512) ? srep[((size_t)(b * 512 + en - 1)) * 256 + j] : 0.f;
    const float c = (st - 1 >= 1 && st - 1 <= 512) ? srep[((size_t)(b * 512 + st - 2)) * 256 + j] : 0.f;
    v = a - c;
  } else {
    const float a = (st >= 1 && st <= 512) ? srep[((size_t)(b * 512 + st - 1)) * 256 + j] : 0.f;
    const float c = (en + 1 >= 1 && en + 1 <= 512) ? srep[((size_t)(b * 512 + en)) * 256 + j] : 0.f;
    v = a - c;
  }
  tmat[(size_t)bt * 256 + j] = v;
}

// ---------------------------------------------------------------------------
// K6: attention scores + context + assemble decoder input.  grid = B*S.
// ---------------------------------------------------------------------------
__global__ __launch_bounds__(256) void k_scores(
    const float* spart, const float* __restrict__ docp, const float* __restrict__ topp,
    const float* __restrict__ v_att, const float* __restrict__ srep,
    const float* __restrict__ docrep, const float* __restrict__ tmat,
    const int* __restrict__ s2t, float* inp)
{
  const int bs = blockIdx.x;
  const int b = bs >> 9;
  const int tid = threadIdx.x;
  const int tp = s2t[bs];
  const float* sp = spart + (size_t)bs * 512;
  const float* dp = docp + (size_t)b * 512;
  const float* tq = topp + ((size_t)(b * 16 + tp)) * 512;
  float ds = 0.f, ts = 0.f;
  #pragma unroll
  for (int r = 0; r < 2; ++r) {
    const int o = tid + r * 256;
    const float s0 = sp[o], v = v_att[o];
    ds += tanhf(s0 + dp[o]) * v;
    ts += tanhf(s0 + tq[o]) * v;
  }
  #pragma unroll
  for (int off = 32; off; off >>= 1) {
    ds += __shfl_down(ds, off);
    ts += __shfl_down(ts, off);
  }
  __shared__ float rds[4], rts[4], wsh[2];
  const int wv = tid >> 6, ln = tid & 63;
  if (ln == 0) { rds[wv] = ds; rts[wv] = ts; }
  __syncthreads();
  if (tid == 0) {
    const float D = rds[0] + rds[1] + rds[2] + rds[3];
    const float T = rts[0] + rts[1] + rts[2] + rts[3];
    const float sum = D + T;
    wsh[0] = D / sum;
    wsh[1] = T / sum;
  }
  __syncthreads();
  const float dw = wsh[0], tw = wsh[1];
  const float sr = srep[(size_t)bs * 256 + tid];
  const float ctx = dw * docrep[(size_t)b * 256 + tid]
                  + tw * tmat[((size_t)(b * 16 + tp)) * 256 + tid];
  float* op = inp + (size_t)bs * 512;
  op[tid] = sr;
  op[256 + tid] = ctx;
}

// ---------------------------------------------------------------------------
// K8: logits[bs] = dot(hbuf[bs], W2) + b2.  grid = B*S, 64 threads.
// ---------------------------------------------------------------------------
__global__ __launch_bounds__(64) void k_logits(
    const float* __restrict__ hbuf, const float* __restrict__ W2,
    const float* __restrict__ b2, float* __restrict__ out)
{
  const int bs = blockIdx.x;
  const int ln = threadIdx.x;
  const float* h = hbuf + (size_t)bs * 128;
  float a = fmaf(h[ln], W2[ln], h[ln + 64] * W2[ln + 64]);
  #pragma unroll
  for (int off = 32; off; off >>= 1) a += __shfl_down(a, off);
  if (ln == 0) out[bs] = a + b2[0];
}

// ---------------------------------------------------------------------------
extern "C" void kernel_launch(void* const* d_in, const int* in_sizes, int n_in,
                              void* d_out, int out_size, void* d_ws, size_t ws_size,
                              hipStream_t stream)
{
  (void)in_sizes; (void)n_in; (void)out_size;

  const int*   word_ids = (const int*)d_in[0];
  const int*   starts   = (const int*)d_in[1];
  const int*   ends     = (const int*)d_in[2];
  const int*   s2t      = (const int*)d_in[3];
  const float* emb      = (const float*)d_in[4];
  const float* Wi_f     = (const float*)d_in[5];
  const float* Wh_f     = (const float*)d_in[6];
  const float* bi_f     = (const float*)d_in[7];
  const float* bh_f     = (const float*)d_in[8];
  const float* Wi_b     = (const float*)d_in[9];
  const float* Wh_b     = (const float*)d_in[10];
  const float* bi_b     = (const float*)d_in[11];
  const float* bh_b     = (const float*)d_in[12];
  const float* W_att    = (const float*)d_in[13];
  const float* v_att    = (const float*)d_in[14];
  const float* W1       = (const float*)d_in[15];
  const float* b1       = (const float*)d_in[16];
  const float* W2       = (const float*)d_in[17];
  const float* b2       = (const float*)d_in[18];
  float* out = (float*)d_out;

  // Workspace layout (bytes).  Aliasing:
  //   spart/inp (33.6MB) overlays gi_f+gi_b (50.3MB, dead after k_gru)
  //   hbuf (8.4MB) overlays sent (19.7MB, dead after the gi GEMMs)
  char* ws = (char*)d_ws;
  if (ws_size < 88440832u) return;   // insufficient scratch -> fail loudly
  float* sent  = (float*)(ws + 0);          // 16384*300*4 = 19,660,800
  float* gi_f  = (float*)(ws + 19660800);   // 16384*384*4 = 25,165,824
  float* gi_b  = (float*)(ws + 44826624);   // 25,165,824
  float* srep  = (float*)(ws + 69992448);   // 16384*256*4 = 16,777,216
  float* hfin  = (float*)(ws + 86769664);   // 2*32*128*4  = 32,768  (== doc_rep flat)
  float* tmat  = (float*)(ws + 86802432);   // 32*16*256*4 = 524,288
  float* docp  = (float*)(ws + 87326720);   // 32*512*4    = 65,536
  float* topp  = (float*)(ws + 87392256);   // 512*512*4   = 1,048,576 -> end 88,440,832
  float* spart = (float*)(ws + 19660800);   // alias gi_f/gi_b
  float* hbuf  = (float*)(ws + 0);          // alias sent

  // 1) sentence means
  k_sent_mean<<<16384, 128, 0, stream>>>(word_ids, emb, sent);
  // 2) input gates (parallel over all steps): gi = sent @ Wi^T + bi
  k_gemm<true, 0><<<dim3(256, 6), 256, 0, stream>>>(16384, 384, 300, sent, 300, Wi_f, 300, gi_f, 384, bi_f);
  k_gemm<true, 0><<<dim3(256, 6), 256, 0, stream>>>(16384, 384, 300, sent, 300, Wi_b, 300, gi_b, 384, bi_b);
  // 3) bidirectional GRU recurrence -> sent_rep (B,S,2H), hfin (2,B,H)
  k_gru<<<64, 256, 0, stream>>>(gi_f, gi_b, Wh_f, Wh_b, bh_f, bh_b, srep, hfin);
  // 4) topic boundary matrix
  k_topic<<<512, 256, 0, stream>>>(starts, ends, srep, tmat);
  // 5) attention partial projections (cat@W_att split by halves of W_att rows)
  k_gemm<false, 0><<<dim3(256, 8), 256, 0, stream>>>(16384, 512, 256, srep, 256, W_att + 256 * 512, 512, spart, 512, nullptr);
  k_gemm<false, 0><<<dim3(1, 8),   256, 0, stream>>>(32,    512, 256, hfin, 256, W_att,            512, docp,  512, nullptr);
  k_gemm<false, 0><<<dim3(8, 8),   256, 0, stream>>>(512,   512, 256, tmat, 256, W_att,            512, topp,  512, nullptr);
  // 6) scores -> weights -> context -> decoder input (in-place over spart)
  k_scores<<<16384, 256, 0, stream>>>(spart, docp, topp, v_att, srep, hfin, tmat, s2t, spart);
  // 7) h = relu(inp @ W1^T + b1)
  k_gemm<true, 1><<<dim3(256, 2), 256, 0, stream>>>(16384, 128, 512, spart, 512, W1, 512, hbuf, 128, b1);
  // 8) logits
  k_logits<<<16384, 64, 0, stream>>>(hbuf, W2, b2, out);
}

// Round 6
// 714.188 us; speedup vs baseline: 1.2396x; 1.2396x over previous
//
#include <hip/hip_runtime.h>

// Problem constants: B=32, S=512, L=20, T=16, E=300, H=128, D=128, V=50000

// Raw workgroup barrier: orders LDS ops (lgkmcnt drain) but does NOT drain
// vmcnt — keeps prefetch global-loads and fire-and-forget stores in flight.
#define LDS_BARRIER() do {                                   \
    asm volatile("s_waitcnt lgkmcnt(0)" ::: "memory");       \
    __builtin_amdgcn_s_barrier();                            \
    asm volatile("" ::: "memory");                           \
  } while (0)

// ---------------------------------------------------------------------------
// K1: sentence embedding mean.  grid = B*S blocks, 128 threads.
// ---------------------------------------------------------------------------
__global__ __launch_bounds__(128) void k_sent_mean(
    const int* __restrict__ wid, const float* __restrict__ emb,
    float* __restrict__ sent)
{
  const int bs = blockIdx.x;
  const int tid = threadIdx.x;
  const int* w = wid + (size_t)bs * 20;
  float a0 = 0.f, a1 = 0.f, a2 = 0.f;
  for (int l = 0; l < 20; ++l) {
    const float* row = emb + (size_t)w[l] * 300;
    a0 += row[tid];
    a1 += row[tid + 128];
    if (tid < 44) a2 += row[tid + 256];
  }
  const float inv = 1.0f / 20.0f;
  float* o = sent + (size_t)bs * 300;
  o[tid] = a0 * inv;
  o[tid + 128] = a1 * inv;
  if (tid < 44) o[tid + 256] = a2 * inv;
}

// ---------------------------------------------------------------------------
// K2: generic fp32 tiled GEMM.  C[M,N] = A[M,K] @ B + bias, optional relu.
// BT=true : B is (N,K) row-major -> C=A@B^T ;  BT=false: B is (K,N) -> C=A@B
// 64x64 tile, 256 threads, 4x4 micro-tile, K chunked by 64.  N % 64 == 0.
// ---------------------------------------------------------------------------
template<bool BT, int ACT>
__global__ __launch_bounds__(256) void k_gemm(
    const int M, const int N, const int K,
    const float* __restrict__ A, const int lda,
    const float* __restrict__ Bm, const int ldb,
    float* __restrict__ C, const int ldc,
    const float* __restrict__ bias)
{
  (void)N;
  __shared__ float As[64][68];
  __shared__ float Bs[64][68];
  const int tid = threadIdx.x;
  const int m0 = blockIdx.x * 64;
  const int n0 = blockIdx.y * 64;
  const int tx = tid & 15;
  const int ty = tid >> 4;
  float acc[4][4] = {};

  for (int kc = 0; kc < K; kc += 64) {
    const int kb = (K - kc < 64) ? (K - kc) : 64;
    #pragma unroll
    for (int r = 0; r < 4; ++r) {
      const int m = r * 16 + ty;
      const int k4 = tx * 4;
      float4 v = make_float4(0.f, 0.f, 0.f, 0.f);
      if (m0 + m < M) {
        const float* ap = A + (size_t)(m0 + m) * lda + kc;
        if (k4 + 4 <= kb) {
          v = *(const float4*)(ap + k4);
        } else {
          float t0 = (k4 + 0 < kb) ? ap[k4 + 0] : 0.f;
          float t1 = (k4 + 1 < kb) ? ap[k4 + 1] : 0.f;
          float t2 = (k4 + 2 < kb) ? ap[k4 + 2] : 0.f;
          float t3 = (k4 + 3 < kb) ? ap[k4 + 3] : 0.f;
          v = make_float4(t0, t1, t2, t3);
        }
      }
      *(float4*)&As[m][k4] = v;
    }
    if (BT) {
      #pragma unroll
      for (int r = 0; r < 4; ++r) {
        const int n = r * 16 + ty;
        const int k4 = tx * 4;
        float4 v = make_float4(0.f, 0.f, 0.f, 0.f);
        const float* bp = Bm + (size_t)(n0 + n) * ldb + kc;
        if (k4 + 4 <= kb) {
          v = *(const float4*)(bp + k4);
        } else {
          float t0 = (k4 + 0 < kb) ? bp[k4 + 0] : 0.f;
          float t1 = (k4 + 1 < kb) ? bp[k4 + 1] : 0.f;
          float t2 = (k4 + 2 < kb) ? bp[k4 + 2] : 0.f;
          float t3 = (k4 + 3 < kb) ? bp[k4 + 3] : 0.f;
          v = make_float4(t0, t1, t2, t3);
        }
        Bs[k4 + 0][n] = v.x;
        Bs[k4 + 1][n] = v.y;
        Bs[k4 + 2][n] = v.z;
        Bs[k4 + 3][n] = v.w;
      }
    } else {
      #pragma unroll
      for (int r = 0; r < 4; ++r) {
        const int kk = r * 16 + ty;
        const int n4 = tx * 4;
        float4 v = make_float4(0.f, 0.f, 0.f, 0.f);
        if (kk < kb) v = *(const float4*)(Bm + (size_t)(kc + kk) * ldb + n0 + n4);
        *(float4*)&Bs[kk][n4] = v;
      }
    }
    __syncthreads();
    #pragma unroll 4
    for (int kk = 0; kk < kb; ++kk) {
      const float4 bv = *(const float4*)&Bs[kk][tx * 4];
      #pragma unroll
      for (int i = 0; i < 4; ++i) {
        const float a = As[ty * 4 + i][kk];
        acc[i][0] = fmaf(a, bv.x, acc[i][0]);
        acc[i][1] = fmaf(a, bv.y, acc[i][1]);
        acc[i][2] = fmaf(a, bv.z, acc[i][2]);
        acc[i][3] = fmaf(a, bv.w, acc[i][3]);
      }
    }
    __syncthreads();
  }

  float bv4[4] = {0.f, 0.f, 0.f, 0.f};
  if (bias != nullptr) {
    #pragma unroll
    for (int j = 0; j < 4; ++j) bv4[j] = bias[n0 + tx * 4 + j];
  }
  #pragma unroll
  for (int i = 0; i < 4; ++i) {
    const int m = m0 + ty * 4 + i;
    if (m < M) {
      float4 o;
      o.x = acc[i][0] + bv4[0];
      o.y = acc[i][1] + bv4[1];
      o.z = acc[i][2] + bv4[2];
      o.w = acc[i][3] + bv4[3];
      if (ACT == 1) {
        o.x = fmaxf(o.x, 0.f); o.y = fmaxf(o.y, 0.f);
        o.z = fmaxf(o.z, 0.f); o.w = fmaxf(o.w, 0.f);
      }
      *(float4*)&C[(size_t)m * ldc + n0 + tx * 4] = o;
    }
  }
}

// ---------------------------------------------------------------------------
// K3: GRU recurrence, one block per (batch, direction).  grid = 64, 512 thr.
//
// Round-5 postmortem: VGPR_Count=132 proved the compiler never kept the
// 192-float/lane weight slice in registers — it re-loaded Wh from L2
// (~200cyc) every step with no co-resident waves to hide it.  This version
// shrinks the per-lane weight slice to 96 floats so residency is cheap:
//   8 waves; wave w: kq = w&3 (K-quarter, 32 floats), rg = w>>2 (row half)
//   lane ln: rows r0=rg*192+ln, r0+64, r0+128  x  K[kq*32 .. kq*32+31]
// => 24 float4 weights + 6 float4 staging + acc ~= 160 VGPR, cap 256
// (__launch_bounds__(512,2)), 2 waves/SIMD for latency overlap.
// Partials: part[4][384] (stride-1 lane access, conflict-free b32).
// Gate math: native __expf / __fdividef (clamped tanh) instead of ocml
// expf/tanhf.  gi double-buffered in 32-step chunks via register staging;
// raw lgkmcnt barriers only (no vmcnt drain on the critical path).
// ---------------------------------------------------------------------------
__global__ __launch_bounds__(512, 2) void k_gru(
    const float* __restrict__ gi_f, const float* __restrict__ gi_b,
    const float* __restrict__ Wh_f, const float* __restrict__ Wh_b,
    const float* __restrict__ bh_f, const float* __restrict__ bh_b,
    float* __restrict__ srep, float* __restrict__ hfin)
{
  const int dir = blockIdx.x & 1;
  const int b = blockIdx.x >> 1;
  const float* gi = (dir ? gi_b : gi_f) + (size_t)b * 512 * 384;
  const float* Wh = dir ? Wh_b : Wh_f;
  const float* bh = dir ? bh_b : bh_f;

  const int tid = threadIdx.x;
  const int wv = tid >> 6;
  const int ln = tid & 63;
  const int kq = wv & 3;        // K-quarter: floats kq*32 .. kq*32+31
  const int rg = wv >> 2;       // row half: rows rg*192 .. rg*192+191
  const int r0 = rg * 192 + ln; // this lane's rows: r0, r0+64, r0+128

  __shared__ __align__(16) float hlds[128];
  __shared__ float partl[4 * 384];                   // [kq][row], stride-1 rows
  __shared__ __align__(16) float gis[2][32 * 384];   // 2 x 48 KB

  // register-resident weights: 3 rows x 32-K-slice = 24 float4 = 96 VGPRs
  float4 w0[8], w1[8], w2[8];
  {
    const float* p = Wh + (size_t)r0 * 128 + kq * 32;
    #pragma unroll
    for (int kk = 0; kk < 8; ++kk) w0[kk] = *(const float4*)(p + kk * 4);
    p += 64 * 128;
    #pragma unroll
    for (int kk = 0; kk < 8; ++kk) w1[kk] = *(const float4*)(p + kk * 4);
    p += 64 * 128;
    #pragma unroll
    for (int kk = 0; kk < 8; ++kk) w2[kk] = *(const float4*)(p + kk * 4);
  }
  const float bh0 = (kq == 0) ? bh[r0] : 0.f;
  const float bh1 = (kq == 0) ? bh[r0 + 64] : 0.f;
  const float bh2 = (kq == 0) ? bh[r0 + 128] : 0.f;

  // prologue: stage chunk 0 synchronously (3072 float4 over 512 threads)
  {
    const int lo0 = dir ? 480 : 0;
    const float4* g4 = (const float4*)(gi + (size_t)lo0 * 384);
    float4* l4 = (float4*)gis[0];
    #pragma unroll
    for (int j = 0; j < 6; ++j) l4[j * 512 + tid] = g4[j * 512 + tid];
  }
  float hreg = 0.f;
  if (tid < 128) hlds[tid] = 0.f;
  LDS_BARRIER();

  const float4* h4q = (const float4*)hlds + kq * 8;
  float4 stg[6];

  for (int c = 0; c < 16; ++c) {
    const int buf = c & 1;
    const int lo = dir ? (480 - 32 * c) : (32 * c);
    // issue next chunk's global loads (held in regs; consumed at chunk end)
    if (c < 15) {
      const int lon = dir ? (480 - 32 * (c + 1)) : (32 * (c + 1));
      const float4* g4 = (const float4*)(gi + (size_t)lon * 384);
      #pragma unroll
      for (int j = 0; j < 6; ++j) stg[j] = g4[j * 512 + tid];
    }

    for (int i = 0; i < 32; ++i) {
      const int sloc = dir ? (31 - i) : i;    // row within chunk
      const int seq = lo + sloc;              // absolute sequence index

      float4 A0 = {0.f, 0.f, 0.f, 0.f};
      float4 A1 = {0.f, 0.f, 0.f, 0.f};
      float4 A2 = {0.f, 0.f, 0.f, 0.f};
      #pragma unroll
      for (int kk = 0; kk < 8; ++kk) {
        const float4 hv = h4q[kk];              // broadcast b128 -> 12 FMA
        A0.x = fmaf(w0[kk].x, hv.x, A0.x);
        A0.y = fmaf(w0[kk].y, hv.y, A0.y);
        A0.z = fmaf(w0[kk].z, hv.z, A0.z);
        A0.w = fmaf(w0[kk].w, hv.w, A0.w);
        A1.x = fmaf(w1[kk].x, hv.x, A1.x);
        A1.y = fmaf(w1[kk].y, hv.y, A1.y);
        A1.z = fmaf(w1[kk].z, hv.z, A1.z);
        A1.w = fmaf(w1[kk].w, hv.w, A1.w);
        A2.x = fmaf(w2[kk].x, hv.x, A2.x);
        A2.y = fmaf(w2[kk].y, hv.y, A2.y);
        A2.z = fmaf(w2[kk].z, hv.z, A2.z);
        A2.w = fmaf(w2[kk].w, hv.w, A2.w);
      }
      partl[kq * 384 + r0]       = (A0.x + A0.y) + (A0.z + A0.w) + bh0;
      partl[kq * 384 + r0 + 64]  = (A1.x + A1.y) + (A1.z + A1.w) + bh1;
      partl[kq * 384 + r0 + 128] = (A2.x + A2.y) + (A2.z + A2.w) + bh2;
      LDS_BARRIER();

      if (tid < 128) {
        const float* grow = &gis[buf][sloc * 384];
        const float ghr = (partl[tid]       + partl[384 + tid])
                        + (partl[768 + tid] + partl[1152 + tid]);
        const float ghz = (partl[tid + 128]        + partl[384 + tid + 128])
                        + (partl[768 + tid + 128]  + partl[1152 + tid + 128]);
        const float ghn = (partl[tid + 256]        + partl[384 + tid + 256])
                        + (partl[768 + tid + 256]  + partl[1152 + tid + 256]);
        const float gir = grow[tid];
        const float giz = grow[tid + 128];
        const float gin = grow[tid + 256];
        const float r = __fdividef(1.f, 1.f + __expf(-(gir + ghr)));
        const float z = __fdividef(1.f, 1.f + __expf(-(giz + ghz)));
        float an = gin + r * ghn;
        an = fminf(fmaxf(an, -15.f), 15.f);
        const float t = __expf(2.f * an);
        const float n = __fdividef(t - 1.f, t + 1.f);
        hreg = (1.f - z) * n + z * hreg;
        hlds[tid] = hreg;
        srep[((size_t)(b * 512 + seq)) * 256 + dir * 128 + tid] = hreg;
      }
      LDS_BARRIER();
    }

    // write staged next chunk into the buffer we just finished reading
    if (c < 15) {
      float4* l4 = (float4*)gis[buf ^ 1];
      #pragma unroll
      for (int j = 0; j < 6; ++j) l4[j * 512 + tid] = stg[j];
      LDS_BARRIER();
    }
  }
  if (tid < 128) hfin[(size_t)dir * 4096 + (size_t)b * 128 + tid] = hreg;
}

// ---------------------------------------------------------------------------
// K4: topic boundary diffs.  grid = B*T = 512, 256 threads.
// ---------------------------------------------------------------------------
__global__ __launch_bounds__(256) void k_topic(
    const int* __restrict__ starts, const int* __restrict__ ends,
    const float* __restrict__ srep, float* __restrict__ tmat)
{
  const int bt = blockIdx.x;
  const int b = bt >> 4;
  const int st = starts[bt], en = ends[bt];
  const int j = threadIdx.x;
  float v;
  if (j < 128) {
    const float a = (en >= 1 && en <= 512) ? srep[((size_t)(b * 512 + en - 1)) * 256 + j] : 0.f;
    const float c = (st - 1 >= 1 && st - 1 <= 512) ? srep[((size_t)(b * 512 + st - 2)) * 256 + j] : 0.f;
    v = a - c;
  } else {
    const float a = (st >= 1 && st <= 512) ? srep[((size_t)(b * 512 + st - 1)) * 256 + j] : 0.f;
    const float c = (en + 1 >= 1 && en + 1 <= 512) ? srep[((size_t)(b * 512 + en)) * 256 + j] : 0.f;
    v = a - c;
  }
  tmat[(size_t)bt * 256 + j] = v;
}

// ---------------------------------------------------------------------------
// K6: attention scores + context + assemble decoder input.  grid = B*S.
// ---------------------------------------------------------------------------
__global__ __launch_bounds__(256) void k_scores(
    const float* spart, const float* __restrict__ docp, const float* __restrict__ topp,
    const float* __restrict__ v_att, const float* __restrict__ srep,
    const float* __restrict__ docrep, const float* __restrict__ tmat,
    const int* __restrict__ s2t, float* inp)
{
  const int bs = blockIdx.x;
  const int b = bs >> 9;
  const int tid = threadIdx.x;
  const int tp = s2t[bs];
  const float* sp = spart + (size_t)bs * 512;
  const float* dp = docp + (size_t)b * 512;
  const float* tq = topp + ((size_t)(b * 16 + tp)) * 512;
  float ds = 0.f, ts = 0.f;
  #pragma unroll
  for (int r = 0; r < 2; ++r) {
    const int o = tid + r * 256;
    const float s0 = sp[o], v = v_att[o];
    ds += tanhf(s0 + dp[o]) * v;
    ts += tanhf(s0 + tq[o]) * v;
  }
  #pragma unroll
  for (int off = 32; off; off >>= 1) {
    ds += __shfl_down(ds, off);
    ts += __shfl_down(ts, off);
  }
  __shared__ float rds[4], rts[4], wsh[2];
  const int wv = tid >> 6, ln = tid & 63;
  if (ln == 0) { rds[wv] = ds; rts[wv] = ts; }
  __syncthreads();
  if (tid == 0) {
    const float D = rds[0] + rds[1] + rds[2] + rds[3];
    const float T = rts[0] + rts[1] + rts[2] + rts[3];
    const float sum = D + T;
    wsh[0] = D / sum;
    wsh[1] = T / sum;
  }
  __syncthreads();
  const float dw = wsh[0], tw = wsh[1];
  const float sr = srep[(size_t)bs * 256 + tid];
  const float ctx = dw * docrep[(size_t)b * 256 + tid]
                  + tw * tmat[((size_t)(b * 16 + tp)) * 256 + tid];
  float* op = inp + (size_t)bs * 512;
  op[tid] = sr;
  op[256 + tid] = ctx;
}

// ---------------------------------------------------------------------------
// K8: logits[bs] = dot(hbuf[bs], W2) + b2.  grid = B*S, 64 threads.
// ---------------------------------------------------------------------------
__global__ __launch_bounds__(64) void k_logits(
    const float* __restrict__ hbuf, const float* __restrict__ W2,
    const float* __restrict__ b2, float* __restrict__ out)
{
  const int bs = blockIdx.x;
  const int ln = threadIdx.x;
  const float* h = hbuf + (size_t)bs * 128;
  float a = fmaf(h[ln], W2[ln], h[ln + 64] * W2[ln + 64]);
  #pragma unroll
  for (int off = 32; off; off >>= 1) a += __shfl_down(a, off);
  if (ln == 0) out[bs] = a + b2[0];
}

// ---------------------------------------------------------------------------
extern "C" void kernel_launch(void* const* d_in, const int* in_sizes, int n_in,
                              void* d_out, int out_size, void* d_ws, size_t ws_size,
                              hipStream_t stream)
{
  (void)in_sizes; (void)n_in; (void)out_size;

  const int*   word_ids = (const int*)d_in[0];
  const int*   starts   = (const int*)d_in[1];
  const int*   ends     = (const int*)d_in[2];
  const int*   s2t      = (const int*)d_in[3];
  const float* emb      = (const float*)d_in[4];
  const float* Wi_f     = (const float*)d_in[5];
  const float* Wh_f     = (const float*)d_in[6];
  const float* bi_f     = (const float*)d_in[7];
  const float* bh_f     = (const float*)d_in[8];
  const float* Wi_b     = (const float*)d_in[9];
  const float* Wh_b     = (const float*)d_in[10];
  const float* bi_b     = (const float*)d_in[11];
  const float* bh_b     = (const float*)d_in[12];
  const float* W_att    = (const float*)d_in[13];
  const float* v_att    = (const float*)d_in[14];
  const float* W1       = (const float*)d_in[15];
  const float* b1       = (const float*)d_in[16];
  const float* W2       = (const float*)d_in[17];
  const float* b2       = (const float*)d_in[18];
  float* out = (float*)d_out;

  // Workspace layout (bytes).  Aliasing:
  //   spart/inp (33.6MB) overlays gi_f+gi_b (50.3MB, dead after k_gru)
  //   hbuf (8.4MB) overlays sent (19.7MB, dead after the gi GEMMs)
  char* ws = (char*)d_ws;
  if (ws_size < 88440832u) return;   // insufficient scratch -> fail loudly
  float* sent  = (float*)(ws + 0);          // 16384*300*4 = 19,660,800
  float* gi_f  = (float*)(ws + 19660800);   // 16384*384*4 = 25,165,824
  float* gi_b  = (float*)(ws + 44826624);   // 25,165,824
  float* srep  = (float*)(ws + 69992448);   // 16384*256*4 = 16,777,216
  float* hfin  = (float*)(ws + 86769664);   // 2*32*128*4  = 32,768  (== doc_rep flat)
  float* tmat  = (float*)(ws + 86802432);   // 32*16*256*4 = 524,288
  float* docp  = (float*)(ws + 87326720);   // 32*512*4    = 65,536
  float* topp  = (float*)(ws + 87392256);   // 512*512*4   = 1,048,576 -> end 88,440,832
  float* spart = (float*)(ws + 19660800);   // alias gi_f/gi_b
  float* hbuf  = (float*)(ws + 0);          // alias sent

  // 1) sentence means
  k_sent_mean<<<16384, 128, 0, stream>>>(word_ids, emb, sent);
  // 2) input gates (parallel over all steps): gi = sent @ Wi^T + bi
  k_gemm<true, 0><<<dim3(256, 6), 256, 0, stream>>>(16384, 384, 300, sent, 300, Wi_f, 300, gi_f, 384, bi_f);
  k_gemm<true, 0><<<dim3(256, 6), 256, 0, stream>>>(16384, 384, 300, sent, 300, Wi_b, 300, gi_b, 384, bi_b);
  // 3) bidirectional GRU recurrence -> sent_rep (B,S,2H), hfin (2,B,H)
  k_gru<<<64, 512, 0, stream>>>(gi_f, gi_b, Wh_f, Wh_b, bh_f, bh_b, srep, hfin);
  // 4) topic boundary matrix
  k_topic<<<512, 256, 0, stream>>>(starts, ends, srep, tmat);
  // 5) attention partial projections (cat@W_att split by halves of W_att rows)
  k_gemm<false, 0><<<dim3(256, 8), 256, 0, stream>>>(16384, 512, 256, srep, 256, W_att + 256 * 512, 512, spart, 512, nullptr);
  k_gemm<false, 0><<<dim3(1, 8),   256, 0, stream>>>(32,    512, 256, hfin, 256, W_att,            512, docp,  512, nullptr);
  k_gemm<false, 0><<<dim3(8, 8),   256, 0, stream>>>(512,   512, 256, tmat, 256, W_att,            512, topp,  512, nullptr);
  // 6) scores -> weights -> context -> decoder input (in-place over spart)
  k_scores<<<16384, 256, 0, stream>>>(spart, docp, topp, v_att, srep, hfin, tmat, s2t, spart);
  // 7) h = relu(inp @ W1^T + b1)
  k_gemm<true, 1><<<dim3(256, 2), 256, 0, stream>>>(16384, 128, 512, spart, 512, W1, 512, hbuf, 128, b1);
  // 8) logits
  k_logits<<<16384, 64, 0, stream>>>(hbuf, W2, b2, out);
}